// Round 1
// baseline (207.623 us; speedup 1.0000x reference)
//
#include <hip/hip_runtime.h>
#include <math.h>

// Dual self-attention block, B=64 C=64 N=256 QK=8 VC=32 S=16, all fp32.
//
// Simplification (verified R1/R2, absmax 0.25): SA per-stroke mask is a
// <=1e-5 logit perturbation -> sum_s softmax == 16 * softmax(10*base).
// stroke_idx / n_strokes numerically dead.
//
// R3 ERRATUM: K == Q here (k_w clones q_w) -> diagonal logits are |q|^2,
// SA log2-logits up to ~215 >> 127. Per-row max is mandatory (two-pass).
//
// R4 (this round): fused attn(GA+SA)+MLP1+MLP2 into ONE kernel per
// 64-position tile. h lives in LDS aliased over the attention accumulator
// AW (union, both ~68 KB); f tile in LDS (17.4 KB). Eliminates the H
// round-trip (33.6 MB), the F RMW + re-reads (~25 MB), and 2 launches.
// MLP phases: lane = position; w1/w2 rows are wave-uniform -> s_load
// (scalar pipe), no weight staging in LDS.

#define EPS    1e-5f
#define LOG2E  1.4426950408889634f

// ws layout in floats
#define OFF_QGA 0u          // [16384][8]
#define OFF_KGA 131072u     // [16384][8]
#define OFF_VGA 262144u     // [16384][32]
#define OFF_QSA 786432u     // [16384][8]
#define OFF_KSA 917504u     // [16384][8]
#define OFF_VSA 1048576u    // [16384][32]
#define OFF_F   1572864u    // [16384][64]  (linear-branch contribs only)

// ---------------------------------------------------------------------------
// K1: projections. grid = B*4 (64 positions/block), 512 thr = 8 waves.
// lane = position; each wave owns 20 of 160 slots (wave-uniform loop ->
// weights via s_load broadcast; inner loop pure v_fmac). Results staged in
// LDS, written out as fully-coalesced float4 runs.
__global__ __launch_bounds__(512) void k_proj(
    const float* __restrict__ x,
    const float* __restrict__ gaq, const float* __restrict__ gak,
    const float* __restrict__ gav, const float* __restrict__ gavb,
    const float* __restrict__ galb, const float* __restrict__ galbbn,
    const float* __restrict__ saq, const float* __restrict__ sak,
    const float* __restrict__ sav, const float* __restrict__ savb,
    const float* __restrict__ salb, const float* __restrict__ salbbn,
    float* ws)
{
    __shared__ float O2[160][65];
    const int lane = threadIdx.x & 63;
    const int wvu  = __builtin_amdgcn_readfirstlane((int)(threadIdx.x >> 6)); // 0..7
    const int b    = blockIdx.x >> 2;
    const int n0   = (blockIdx.x & 3) << 6;
    const int p0g  = blockIdx.x << 6;

    float xr[64];
    const float* xb = x + (size_t)(b * 64) * 256 + n0 + lane;
    #pragma unroll
    for (int c = 0; c < 64; ++c) xr[c] = xb[c * 256];

    for (int i = 0; i < 20; ++i) {
        const int slot = wvu * 20 + i;           // wave-uniform
        const float* wr; float mul = 1.f, add = 0.f;
        if (slot < 8)        { wr = gaq + slot * 64; }
        else if (slot < 16)  { wr = gak + (slot - 8) * 64; }
        else if (slot < 48)  { int vc = slot - 16; wr = gav + vc * 64; add = gavb[vc]; }
        else if (slot < 56)  { wr = saq + (slot - 48) * 64; }
        else if (slot < 64)  { wr = sak + (slot - 56) * 64; }
        else if (slot < 96)  { int vc = slot - 64; wr = sav + vc * 64; add = savb[vc]; }
        else if (slot < 128) { int vc = slot - 96; wr = galb + vc * 64;
                               float s = galbbn[vc] * rsqrtf(galbbn[96 + vc] + EPS);
                               mul = s; add = galbbn[32 + vc] - galbbn[64 + vc] * s; }
        else                 { int vc = slot - 128; wr = salb + vc * 64;
                               float s = salbbn[vc] * rsqrtf(salbbn[96 + vc] + EPS);
                               mul = s; add = salbbn[32 + vc] - salbbn[64 + vc] * s; }
        float acc = 0.f;
        #pragma unroll
        for (int c = 0; c < 64; ++c) acc = fmaf(wr[c], xr[c], acc);
        O2[slot][lane] = acc * mul + add;
    }
    __syncthreads();

    // coalesced copy-out: 2560 float4s
    for (int t = threadIdx.x; t < 2560; t += 512) {
        int u, rb, l; unsigned g;
        if (t < 128)       { u = t;        rb = 0;   l = 1; g = OFF_QGA; }
        else if (t < 256)  { u = t - 128;  rb = 8;   l = 1; g = OFF_KGA; }
        else if (t < 768)  { u = t - 256;  rb = 16;  l = 3; g = OFF_VGA; }
        else if (t < 896)  { u = t - 768;  rb = 48;  l = 1; g = OFF_QSA; }
        else if (t < 1024) { u = t - 896;  rb = 56;  l = 1; g = OFF_KSA; }
        else if (t < 1536) { u = t - 1024; rb = 64;  l = 3; g = OFF_VSA; }
        else               { u = t - 1536; rb = 96;  l = 4; g = OFF_F;   }
        const int p    = u >> l;
        const int off4 = u & ((1 << l) - 1);
        const int row  = rb + off4 * 4;
        float4 v;
        v.x = O2[row + 0][p]; v.y = O2[row + 1][p];
        v.z = O2[row + 2][p]; v.w = O2[row + 3][p];
        *(float4*)(ws + g + (size_t)(p0g + p) * (4u << l) + off4 * 4) = v;
    }
}

// ---------------------------------------------------------------------------
// K2: fused GA-attn + SA-attn + MLP1 + MLP2. grid = 256 (b, 64-pos tile),
// 512 thr = 8 waves.
//  attn : wave = 32-key m-chunk, lane = q position. Two passes (chunk max,
//         then exp+PV), chunk combine (exp-rescale) accumulated into the
//         LDS f tile (preloaded with the linear-branch contribs from ws.F).
//  mlp1 : lane = position, wave = 32-j group; f row held in 16 float4 regs;
//         w1 rows wave-uniform -> s_load. h -> LDS (aliases AW).
//  mlp2 : lane = position, wave = 8-channel group; h row per-lane ds_b128
//         (stride 268 -> 16B-slot spread), w2 rows wave-uniform -> s_load.
//         Residual from fL, out stores 64-contiguous (coalesced).
// LDS: MW/ZW 4K + fL 17.4K + union(AW 67.6K | hL 68.6K) = 90.4 KB.
__global__ __launch_bounds__(512) void k_fused(
    const float* __restrict__ wsr, const float* __restrict__ gabnp,
    const float* __restrict__ sabnp, const float* __restrict__ Fin,
    const float* __restrict__ w1, const float* __restrict__ bn1,
    const float* __restrict__ w2, const float* __restrict__ bn2,
    float* __restrict__ out)
{
    __shared__ float MW[8][64];
    __shared__ float ZW[8][64];
    __shared__ __align__(16) float fL[64][68];
    union USH {
        float AW[8][64][33];
        float hL[64][268];
    };
    __shared__ __align__(16) USH U;

    const int lane = threadIdx.x & 63;
    const int w    = __builtin_amdgcn_readfirstlane((int)(threadIdx.x >> 6)); // 0..7
    const int b    = blockIdx.x >> 2;
    const int n0   = (blockIdx.x & 3) << 6;

    // stage f tile (linear-branch contributions written by k_proj)
    {
        const float4* src = (const float4*)(Fin + (size_t)(b * 256 + n0) * 64);
        #pragma unroll
        for (int t0 = 0; t0 < 2; ++t0) {
            const int t = (int)threadIdx.x + t0 * 512;
            float4 v = src[t];
            *(float4*)&fL[t >> 4][(t & 15) << 2] = v;
        }
    }
    // first __syncthreads (after AW writes) also orders staging vs combine.

    const int p  = b * 256 + n0 + lane;
    const int m0 = w << 5;

    for (int which = 0; which < 2; ++which) {
        const unsigned ro = which ? 786432u : 0u;
        const float* Q = wsr + OFF_QGA + ro;
        const float* K = wsr + OFF_KGA + ro;
        const float* V = wsr + OFF_VGA + ro;
        const float* bnp = which ? sabnp : gabnp;
        const float factor   = which ? 3.5355339059327378f : 0.35355339059327378f;
        const float outscale = which ? 16.f : 1.f;
        const int   choff    = which << 5;

        const float fl = factor * LOG2E;
        float4 qa = *(const float4*)(Q + (size_t)p * 8);
        float4 qb = *(const float4*)(Q + (size_t)p * 8 + 4);
        qa.x *= fl; qa.y *= fl; qa.z *= fl; qa.w *= fl;
        qb.x *= fl; qb.y *= fl; qb.z *= fl; qb.w *= fl;
        const float* Kb = K + (size_t)(b * 256 + m0) * 8;
        const float* Vb = V + (size_t)(b * 256 + m0) * 32;

        // pass 1: chunk max (log2 units)
        float M = -1e30f;
        #pragma unroll 4
        for (int i = 0; i < 32; ++i) {
            const float4 k0 = *(const float4*)(Kb + i * 8);
            const float4 k1 = *(const float4*)(Kb + i * 8 + 4);
            float t0 = qa.x * k0.x + qa.y * k0.y + qa.z * k0.z + qa.w * k0.w;
            float t1 = qb.x * k1.x + qb.y * k1.y + qb.z * k1.z + qb.w * k1.w;
            M = fmaxf(M, t0 + t1);
        }
        // pass 2: exp + PV accumulate
        float Z = 0.f;
        float acc[32];
        #pragma unroll
        for (int j = 0; j < 32; ++j) acc[j] = 0.f;
        #pragma unroll 2
        for (int i = 0; i < 32; ++i) {
            const float4 k0 = *(const float4*)(Kb + i * 8);
            const float4 k1 = *(const float4*)(Kb + i * 8 + 4);
            float t0 = qa.x * k0.x + qa.y * k0.y + qa.z * k0.z + qa.w * k0.w;
            float t1 = qb.x * k1.x + qb.y * k1.y + qb.z * k1.z + qb.w * k1.w;
            float pv = exp2f(t0 + t1 - M);
            Z += pv;
            const float* vr = Vb + (size_t)i * 32;
            #pragma unroll
            for (int j4 = 0; j4 < 8; ++j4) {
                float4 vv = *(const float4*)(vr + j4 * 4);
                acc[j4 * 4 + 0] = fmaf(pv, vv.x, acc[j4 * 4 + 0]);
                acc[j4 * 4 + 1] = fmaf(pv, vv.y, acc[j4 * 4 + 1]);
                acc[j4 * 4 + 2] = fmaf(pv, vv.z, acc[j4 * 4 + 2]);
                acc[j4 * 4 + 3] = fmaf(pv, vv.w, acc[j4 * 4 + 3]);
            }
        }
        MW[w][lane] = M;
        ZW[w][lane] = Z;
        #pragma unroll
        for (int j = 0; j < 32; ++j) U.AW[w][lane][j] = acc[j];
        __syncthreads();

        // combine chunks (max-rescale) + BN, accumulate into fL
        {
            const int vc = threadIdx.x & 31;
            const int rg = threadIdx.x >> 5;          // 0..15, 4 rows each
            const float g  = bnp[vc], be = bnp[32 + vc],
                        mn = bnp[64 + vc], va = bnp[96 + vc];
            const float gs   = g * rsqrtf(va + EPS);
            const float s    = gs * outscale;
            const float bias = be - mn * gs;
            for (int r = 0; r < 4; ++r) {
                const int rr = (rg << 2) + r;
                float Mx = MW[0][rr];
                #pragma unroll
                for (int u = 1; u < 8; ++u) Mx = fmaxf(Mx, MW[u][rr]);
                float Zt = 0.f, A = 0.f;
                #pragma unroll
                for (int u = 0; u < 8; ++u) {
                    float cw = exp2f(MW[u][rr] - Mx);
                    Zt += ZW[u][rr] * cw;
                    A   = fmaf(U.AW[u][rr][vc], cw, A);
                }
                fL[rr][choff + vc] += (A / Zt) * s + bias;
            }
        }
        __syncthreads();   // combine reads done before AW reuse / hL write
    }

    // ---- MLP phase 1: h[p][j] = relu(bn1(w1 @ f[p])), lane = p -------------
    float4 fr[16];
    #pragma unroll
    for (int c4 = 0; c4 < 16; ++c4)
        fr[c4] = *(const float4*)&fL[lane][c4 << 2];

    const int j0 = w << 5;
    for (int jj = 0; jj < 32; jj += 4) {
        const float* wrow = w1 + (size_t)(j0 + jj) * 64;
        float a0 = 0.f, a1 = 0.f, a2 = 0.f, a3 = 0.f;
        #pragma unroll
        for (int c4 = 0; c4 < 16; ++c4) {
            const float4 f  = fr[c4];
            const float4 w0 = *(const float4*)(wrow +       (c4 << 2)); // s_load
            const float4 w1v= *(const float4*)(wrow +  64 + (c4 << 2));
            const float4 w2v= *(const float4*)(wrow + 128 + (c4 << 2));
            const float4 w3v= *(const float4*)(wrow + 192 + (c4 << 2));
            a0 += w0.x * f.x + w0.y * f.y + w0.z * f.z + w0.w * f.w;
            a1 += w1v.x * f.x + w1v.y * f.y + w1v.z * f.z + w1v.w * f.w;
            a2 += w2v.x * f.x + w2v.y * f.y + w2v.z * f.z + w2v.w * f.w;
            a3 += w3v.x * f.x + w3v.y * f.y + w3v.z * f.z + w3v.w * f.w;
        }
        const int j = j0 + jj;
        float4 hv;
        { float g = bn1[j+0], be = bn1[256+j+0], mn = bn1[512+j+0], va = bn1[768+j+0];
          float s = g * rsqrtf(va + EPS); hv.x = fmaxf(a0 * s + (be - mn * s), 0.f); }
        { float g = bn1[j+1], be = bn1[256+j+1], mn = bn1[512+j+1], va = bn1[768+j+1];
          float s = g * rsqrtf(va + EPS); hv.y = fmaxf(a1 * s + (be - mn * s), 0.f); }
        { float g = bn1[j+2], be = bn1[256+j+2], mn = bn1[512+j+2], va = bn1[768+j+2];
          float s = g * rsqrtf(va + EPS); hv.z = fmaxf(a2 * s + (be - mn * s), 0.f); }
        { float g = bn1[j+3], be = bn1[256+j+3], mn = bn1[512+j+3], va = bn1[768+j+3];
          float s = g * rsqrtf(va + EPS); hv.w = fmaxf(a3 * s + (be - mn * s), 0.f); }
        *(float4*)&U.hL[lane][j] = hv;        // stride 268 -> slot spread
    }
    __syncthreads();

    // ---- MLP phase 2: out[c][p] = relu(bn2(w2 @ h[p]) + f[p][c]) ----------
    float a2c[8];
    #pragma unroll
    for (int k = 0; k < 8; ++k) a2c[k] = 0.f;
    const float* w2base = w2 + (size_t)(w << 3) * 256;
    for (int j4 = 0; j4 < 64; ++j4) {
        const float4 hv = *(const float4*)&U.hL[lane][j4 << 2]; // per-lane b128
        #pragma unroll
        for (int k = 0; k < 8; ++k) {
            const float4 wv = *(const float4*)(w2base + k * 256 + (j4 << 2)); // s_load
            a2c[k] += wv.x * hv.x + wv.y * hv.y + wv.z * hv.z + wv.w * hv.w;
        }
    }
    #pragma unroll
    for (int k = 0; k < 8; ++k) {
        const int c = (w << 3) + k;
        const float g = bn2[c], be = bn2[64 + c], mn = bn2[128 + c], va = bn2[192 + c];
        const float s = g * rsqrtf(va + EPS);
        const float v = a2c[k] * s + (be - mn * s) + fL[lane][c];
        out[(size_t)(b * 64 + c) * 256 + n0 + lane] = fmaxf(v, 0.f);
    }
}

// ---------------------------------------------------------------------------
extern "C" void kernel_launch(void* const* d_in, const int* in_sizes, int n_in,
                              void* d_out, int out_size, void* d_ws, size_t ws_size,
                              hipStream_t stream) {
    const float* x      = (const float*)d_in[0];
    // d_in[1] stroke_idx, d_in[2] n_strokes: numerically dead (see header)
    const float* gaq    = (const float*)d_in[3];
    const float* gak    = (const float*)d_in[4];
    const float* gav    = (const float*)d_in[5];
    const float* gavb   = (const float*)d_in[6];
    const float* gabnp  = (const float*)d_in[7];
    const float* galb   = (const float*)d_in[8];
    const float* galbbn = (const float*)d_in[9];
    const float* saq    = (const float*)d_in[10];
    const float* sak    = (const float*)d_in[11];
    const float* sav    = (const float*)d_in[12];
    const float* savb   = (const float*)d_in[13];
    const float* sabnp  = (const float*)d_in[14];
    const float* salb   = (const float*)d_in[15];
    const float* salbbn = (const float*)d_in[16];
    const float* w1     = (const float*)d_in[17];
    const float* bn1    = (const float*)d_in[18];
    const float* w2     = (const float*)d_in[19];
    const float* bn2    = (const float*)d_in[20];
    float* ws   = (float*)d_ws;
    float* outp = (float*)d_out;

    k_proj<<<dim3(256), dim3(512), 0, stream>>>(
        x, gaq, gak, gav, gavb, galb, galbbn,
        saq, sak, sav, savb, salb, salbbn, ws);

    k_fused<<<dim3(256), dim3(512), 0, stream>>>(
        ws, gabnp, sabnp, ws + OFF_F, w1, bn1, w2, bn2, outp);
}